// Round 1
// baseline (58.363 us; speedup 1.0000x reference)
//
#include <hip/hip_runtime.h>

#define BB 4
#define RR 160
#define HH 128
#define WW 128
#define CC 64
#define NREG 32
#define PH 7
#define PW 7
#define IOU_THRF 0.4f

// floor division (Python // semantics) for possibly-negative numerators
__device__ __forceinline__ int fdiv(int a, int b) {
    int q = a / b, r = a % b;
    return (r != 0 && ((r < 0) != (b < 0))) ? q - 1 : q;
}

__device__ __forceinline__ void fix_span(int& lo, int& hi, int p, int s) {
    int pad = p - (hi - lo);
    bool fmin = lo < fdiv(pad, 2);
    bool fmax = (s - hi) < fdiv(1 + pad, 2);
    bool sym = (pad > 0) && !(fmin || fmax);
    int lo2 = sym ? lo - fdiv(pad, 2) : lo;
    int hi2 = sym ? hi + fdiv(1 + pad, 2) : hi;
    if ((pad > 0) && fmin) { lo2 = 0; hi2 = p; }
    if ((pad > 0) && fmax) { lo2 = s - p; hi2 = s; }
    lo = lo2; hi = hi2;
}

// One block per batch image. Sequential NMS (order-preserving, no sort),
// then select first 32 kept (pad with R-1), then clip to int spans >= 7.
__global__ __launch_bounds__(256)
void nms_clip_kernel(const float* __restrict__ roi, int* __restrict__ boxes_out) {
    const int b = blockIdx.x;
    const int tid = threadIdx.x;

    __shared__ float sx[RR], sy[RR], sw[RR], sh[RR], sarea[RR];
    __shared__ int keep[RR];
    __shared__ int sel[NREG];

    const float* rb = roi + (size_t)b * RR * 4;
    for (int j = tid; j < RR; j += blockDim.x) {
        float x = rb[j * 4 + 0], y = rb[j * 4 + 1];
        float w = rb[j * 4 + 2], h = rb[j * 4 + 3];
        sx[j] = x; sy[j] = y; sw[j] = w; sh[j] = h;
        sarea[j] = __fmul_rn(w, h);
        keep[j] = 1;
    }
    __syncthreads();

    const int j = tid;  // thread j owns box j (threads >= RR idle)
    for (int i = 0; i < RR - 1; ++i) {
        if (j > i && j < RR && keep[i]) {
            float xa = fmaxf(sx[i], sx[j]);
            float ya = fmaxf(sy[i], sy[j]);
            float xb = fminf(__fadd_rn(sx[i], sw[i]), __fadd_rn(sx[j], sw[j]));
            float yb = fminf(__fadd_rn(sy[i], sh[i]), __fadd_rn(sy[j], sh[j]));
            float iw = fmaxf(__fsub_rn(xb, xa), 0.0f);
            float ih = fmaxf(__fsub_rn(yb, ya), 0.0f);
            float inter = __fmul_rn(iw, ih);
            float denom = __fsub_rn(__fadd_rn(sarea[i], sarea[j]), inter);
            float iou = __fdiv_rn(inter, denom);
            if (iou > IOU_THRF) keep[j] = 0;
        }
        __syncthreads();
    }

    if (tid == 0) {
        int cnt = 0;
        for (int k = 0; k < RR && cnt < NREG; ++k)
            if (keep[k]) sel[cnt++] = k;
        for (; cnt < NREG; ++cnt) sel[cnt] = RR - 1;
    }
    __syncthreads();

    if (tid < NREG) {
        int src = sel[tid];
        float fx = sx[src], fy = sy[src], fw = sw[src], fh = sh[src];
        int x0 = max(0, (int)fx);
        int y0 = max(0, (int)fy);
        int x1 = min(WW, (int)__fadd_rn(fx, fw));
        int y1 = min(HH, (int)__fadd_rn(fy, fh));
        fix_span(x0, x1, PW, WW);
        fix_span(y0, y1, PH, HH);
        int* o = boxes_out + ((size_t)b * NREG + tid) * 4;
        o[0] = x0; o[1] = y0; o[2] = x1 - x0; o[3] = y1 - y0;
    }
}

// One block per (b, region, pool-row i); thread = (pool-col j, channel c).
// Channel fastest -> coalesced 256B loads per wave.
__global__ __launch_bounds__(PW * CC)
void pool_kernel(const float* __restrict__ feat, const int* __restrict__ boxes,
                 float* __restrict__ out) {
    const int blk = blockIdx.x;
    const int i = blk % PH;
    const int n = (blk / PH) % NREG;
    const int b = blk / (PH * NREG);
    const int tid = threadIdx.x;
    const int jj = tid / CC;   // 0..6
    const int c  = tid % CC;   // 0..63

    const int* bx = boxes + ((size_t)b * NREG + n) * 4;
    const int x0 = bx[0], y0 = bx[1], w = bx[2], h = bx[3];
    const int hs = h / PH, wss = w / PW;

    const int r0 = y0 + i * hs;
    const int r1 = (i == PH - 1) ? (y0 + h) : (r0 + hs);
    const int c0 = x0 + jj * wss;
    const int c1 = (jj == PW - 1) ? (x0 + w) : (c0 + wss);

    const float* fb = feat + (size_t)b * HH * WW * CC;
    float v = -INFINITY;
    for (int r = r0; r < r1; ++r) {
        const float* row = fb + ((size_t)r * WW) * CC + c;
        for (int col = c0; col < c1; ++col) {
            v = fmaxf(v, row[(size_t)col * CC]);
        }
    }
    out[((((size_t)b * NREG + n) * PH + i) * PW + jj) * CC + c] = v;
}

extern "C" void kernel_launch(void* const* d_in, const int* in_sizes, int n_in,
                              void* d_out, int out_size, void* d_ws, size_t ws_size,
                              hipStream_t stream) {
    const float* features = (const float*)d_in[0];
    const float* roi      = (const float*)d_in[1];
    float* out = (float*)d_out;
    int* boxes = (int*)d_ws;   // BB*NREG*4 ints = 2 KB

    nms_clip_kernel<<<BB, 256, 0, stream>>>(roi, boxes);
    pool_kernel<<<BB * NREG * PH, PW * CC, 0, stream>>>(features, boxes, out);
}